// Round 10
// baseline (129.355 us; speedup 1.0000x reference)
//
#include <hip/hip_runtime.h>

#define Nn 768
#define Dd 128

typedef __attribute__((ext_vector_type(8))) short bf16x8;
typedef __attribute__((ext_vector_type(4))) float f32x4;
typedef __attribute__((ext_vector_type(4))) int   i32x4;

static __device__ __forceinline__ unsigned short f2bf(float f) {
  unsigned int u = __builtin_bit_cast(unsigned int, f);
  u += 0x7fffu + ((u >> 16) & 1u);   // RNE
  return (unsigned short)(u >> 16);
}
// packed f32 pair -> [bf16(hi):bf16(lo)] in one VALU op (RNE)
static __device__ __forceinline__ unsigned int cvtpk(float lo, float hi) {
  unsigned int r;
  asm("v_cvt_pk_bf16_f32 %0, %1, %2" : "=v"(r) : "v"(lo), "v"(hi));
  return r;
}

// left[i][e] = sum_d x[i][d] * W_in[e][d] + b_in[e]; bf16 copy + f32 copy.
__global__ __launch_bounds__(128)
void k_left(const float* __restrict__ x, const float* __restrict__ Win,
            const float* __restrict__ bin, unsigned short* __restrict__ left,
            float* __restrict__ left_f) {
  __shared__ float sx[Dd];
  const int i = blockIdx.x;
  const int e = threadIdx.x;
  sx[e] = x[i * Dd + e];
  __syncthreads();
  const float4* wrow = (const float4*)(Win + e * Dd);
  float a0 = 0.f, a1 = 0.f, a2 = 0.f, a3 = 0.f;
#pragma unroll
  for (int d4 = 0; d4 < Dd / 4; d4 += 4) {
    float4 w0 = wrow[d4+0], w1 = wrow[d4+1], w2 = wrow[d4+2], w3 = wrow[d4+3];
    a0 += sx[4*d4+ 0]*w0.x + sx[4*d4+ 1]*w0.y + sx[4*d4+ 2]*w0.z + sx[4*d4+ 3]*w0.w;
    a1 += sx[4*d4+ 4]*w1.x + sx[4*d4+ 5]*w1.y + sx[4*d4+ 6]*w1.z + sx[4*d4+ 7]*w1.w;
    a2 += sx[4*d4+ 8]*w2.x + sx[4*d4+ 9]*w2.y + sx[4*d4+10]*w2.z + sx[4*d4+11]*w2.w;
    a3 += sx[4*d4+12]*w3.x + sx[4*d4+13]*w3.y + sx[4*d4+14]*w3.z + sx[4*d4+15]*w3.w;
  }
  const float v = ((a0 + a1) + (a2 + a3)) + bin[e];
  left_f[i * Dd + e] = v;
  left[i * Dd + e]   = f2bf(v);
}

// out[i, j, e] = sum_d left[j][d] * (W_out[e][d]*left[i][d]) + b_out[e]
// Barrier-free, LDS-free k_outer: each wave owns 128 j x 32 e of the
// (i, jt) tile. Its 8 B-fragments (scaled Wout) are computed in registers
// from L2-hot Wout/left_f; A-fragments read from global left (L1-shared
// across the 4 waves). All loads precede all stores -> issue-and-forget.
__global__ __launch_bounds__(256, 4)
void k_outer(const unsigned short* __restrict__ left,
             const float* __restrict__ left_f,
             const float* __restrict__ Wout,
             const float* __restrict__ bout, float* __restrict__ out) {
  const int jt = blockIdx.x;   // 0..5
  const int i  = blockIdx.y;   // 0..767
  const int t  = threadIdx.x;  // 0..255

  const int wid  = t >> 6;        // wave 0..3 -> e rows [wid*32, wid*32+32)
  const int lane = t & 63;
  const int l15  = lane & 15;
  const int koct = (lane >> 4) * 8;   // k-octet within a 32-wide k-block

  // ---- in-register B staging: B[m][kb] covers e = wid*32 + m*16 + l15
  bf16x8 B[2][4];
  float bias[2];
  const float* lfi = left_f + i * Dd;
#pragma unroll
  for (int m = 0; m < 2; ++m) {
    const int e = wid * 32 + m * 16 + l15;
    bias[m] = bout[e];
    const float* wrow = Wout + e * Dd;
#pragma unroll
    for (int kb = 0; kb < 4; ++kb) {
      const int k = kb * 32 + koct;
      const float4* wp = (const float4*)(wrow + k);
      const float4* lp = (const float4*)(lfi + k);
      float4 w0 = wp[0], w1 = wp[1];
      float4 f0 = lp[0], f1 = lp[1];
      i32x4 vb;
      vb[0] = (int)cvtpk(w0.x * f0.x, w0.y * f0.y);
      vb[1] = (int)cvtpk(w0.z * f0.z, w0.w * f0.w);
      vb[2] = (int)cvtpk(w1.x * f1.x, w1.y * f1.y);
      vb[3] = (int)cvtpk(w1.z * f1.z, w1.w * f1.w);
      B[m][kb] = __builtin_bit_cast(bf16x8, vb);
    }
  }

  // ---- MFMA: A from global left (L1-hot; identical frags across waves)
  f32x4 acc[8][2] = {};   // [j-frag][e-chunk]
  const unsigned short* gA0 = left + (size_t)(jt * 128 + l15) * Dd + koct;
#pragma unroll
  for (int jf = 0; jf < 8; ++jf) {
    const unsigned short* gA = gA0 + (size_t)jf * 16 * Dd;
#pragma unroll
    for (int kb = 0; kb < 4; ++kb) {
      bf16x8 a = *(const bf16x8*)(gA + kb * 32);
      acc[jf][0] = __builtin_amdgcn_mfma_f32_16x16x32_bf16(a, B[0][kb], acc[jf][0], 0, 0, 0);
      acc[jf][1] = __builtin_amdgcn_mfma_f32_16x16x32_bf16(a, B[1][kb], acc[jf][1], 0, 0, 0);
    }
  }

  // ---- epilogue (proven pattern): row(j) = (lane>>4)*4 + r, col(e) per m.
  const int e0 = wid * 32 + l15;
#pragma unroll
  for (int jf = 0; jf < 8; ++jf) {
#pragma unroll
    for (int r = 0; r < 4; ++r) {
      const int j = jt * 128 + jf * 16 + (lane >> 4) * 4 + r;
      float* orow = out + ((size_t)i * Nn + j) * Dd;
      orow[e0]      = acc[jf][0][r] + bias[0];
      orow[e0 + 16] = acc[jf][1][r] + bias[1];
    }
  }
}

extern "C" void kernel_launch(void* const* d_in, const int* in_sizes, int n_in,
                              void* d_out, int out_size, void* d_ws, size_t ws_size,
                              hipStream_t stream) {
  const float* x    = (const float*)d_in[0];
  const float* Win  = (const float*)d_in[1];
  const float* bin  = (const float*)d_in[2];
  const float* Wout = (const float*)d_in[3];
  const float* bout = (const float*)d_in[4];
  float* out = (float*)d_out;
  unsigned short* left  = (unsigned short*)d_ws;                 // 192 KiB bf16
  float*          left_f = (float*)((char*)d_ws + 256 * 1024);   // 384 KiB f32

  k_left<<<Nn, Dd, 0, stream>>>(x, Win, bin, left, left_f);
  dim3 grid(Nn / 128, Nn);
  k_outer<<<grid, 256, 0, stream>>>(left, left_f, Wout, bout, out);
}